// Round 8
// baseline (262.541 us; speedup 1.0000x reference)
//
#include <hip/hip_runtime.h>
#include <math.h>

#define B_ 128
#define S_ 1024
#define D_ 256          // D == A == O == 256
#define XP 264          // LDS bf16 row pitch for x/v tile (528 B, 16B-aligned)
#define TP 68           // LDS fp32 row pitch for transpose buffer (272 B, 16B-aligned)
#define ROWS 16         // rows per block == rows per wave (1-wave workgroups)

using bf16x8 = __attribute__((ext_vector_type(8))) __bf16;
using bf16x4 = __attribute__((ext_vector_type(4))) __bf16;
using f32x4  = __attribute__((ext_vector_type(4))) float;

__device__ __forceinline__ float qred_add(float v) {   // reduce across 16-lane group
    v += __shfl_xor(v, 1); v += __shfl_xor(v, 2);
    v += __shfl_xor(v, 4); v += __shfl_xor(v, 8);
    return v;
}
__device__ __forceinline__ float wred_add(float x) {
#pragma unroll
    for (int off = 32; off > 0; off >>= 1) x += __shfl_xor(x, off, 64);
    return x;
}

// ---- prep: pack W, Uo (fp32 row-major [k][n]) into B-fragment-linear bf16.
__global__ __launch_bounds__(256) void k_prep(
    const float* __restrict__ W, const float* __restrict__ Uo,
    __bf16* __restrict__ Wf, __bf16* __restrict__ Uf)
{
    const int e = blockIdx.x * 256 + threadIdx.x;   // 0..65535
    const int frag = e >> 9, rem = e & 511;
    const int lane = rem >> 3, j = rem & 7;
    const int kk = frag >> 4, tn = frag & 15;
    const int k = kk * 32 + (lane >> 4) * 8 + j;
    const int n = tn * 16 + (lane & 15);
    Wf[e] = (__bf16)W[k * 256 + n];
    Uf[e] = (__bf16)Uo[k * 256 + n];
}

// ---- main fused kernel: ONE wave per block, 16 rows x 256 cols.
// Zero barriers, zero cross-wave reductions: every row reduction (||t||^2, vu,
// beta-sum) is an in-register 16-lane qred. LDS is a wave-private x/v tile
// (+ aliased transpose buf) ordered by lgkmcnt only. Rounds 1-6 lesson: perf
// tracks INDEPENDENT streams/CU (round-6: more waves in lockstep = worse).
// Here every resident wave is its own stream (12-16/CU vs round-4's ~2.5 blocks).
// (64,3): budget 170, no spill by construction (demand ~120 = acc64 + ~55 V).
// Falsifier: WRITE_SIZE > ~150,000 KB = spill = revert.
__global__ __launch_bounds__(64, 3) void k_rows(
    const float* __restrict__ x, const float* __restrict__ mask,
    const __bf16* __restrict__ Wf, const float* __restrict__ bo,
    const float* __restrict__ u, const __bf16* __restrict__ Uf,
    float* __restrict__ e_out,    // [B*S] unnormalized exp(vu)*mask (alphas region)
    float* __restrict__ betas,    // [B*S, 256]
    float* __restrict__ part,     // [gridDim.x, 256] per-block out partials (ws)
    float* __restrict__ outraw,   // [B,256] atomic fallback accumulator
    const int use_part)
{
    // xs (bf16 x/v tile, 16*XP*2 = 8448 B) aliased with trans (16*TP*4 = 4352 B)
    __shared__ __align__(16) char smem[ROWS * XP * 2];
    __bf16* xs   = (__bf16*)smem;
    float* trans = (float*)smem;
    const int lane = threadIdx.x & 63;
    const int quad = lane >> 4, c = lane & 15;
    const int row0 = blockIdx.x * ROWS;
    const bf16x8* Wf8 = (const bf16x8*)Wf;
    const bf16x8* Uf8 = (const bf16x8*)Uf;

    // stage x[16][256] fp32 -> bf16 LDS (16 float4/thread, 1 row per iteration)
    {
        const float4* xg = (const float4*)(x + (size_t)row0 * D_);
#pragma unroll
        for (int it = 0; it < 16; ++it) {
            const int fg = it * 64 + lane;         // float4 index; row = it
            const float4 t = xg[fg];
            bf16x4 h; h[0] = (__bf16)t.x; h[1] = (__bf16)t.y; h[2] = (__bf16)t.z; h[3] = (__bf16)t.w;
            *(bf16x4*)(xs + it * XP + (fg & 63) * 4) = h;
        }
    }
    asm volatile("s_waitcnt lgkmcnt(0)" ::: "memory");  // cross-lane RAW: x tile visible

    // ---- GEMM1: t = x @ W  (16 rows x 256 cols; acc[16] = 64 regs, reused by GEMM2)
    f32x4 acc[16];
#pragma unroll
    for (int j = 0; j < 16; ++j) acc[j] = (f32x4){0.f, 0.f, 0.f, 0.f};
#pragma unroll
    for (int kk = 0; kk < 8; ++kk) {
        const bf16x8 a = *(const bf16x8*)(xs + c * XP + kk * 32 + quad * 8);
#pragma unroll
        for (int j = 0; j < 16; ++j) {
            const bf16x8 b = Wf8[(kk * 16 + j) * 64 + lane];
            acc[j] = __builtin_amdgcn_mfma_f32_16x16x32_bf16(a, b, acc[j], 0, 0, 0);
        }
    }

    // bias + in-register row norms (qred over the 16 c-lanes = full 256-col sum)
#pragma unroll
    for (int j = 0; j < 16; ++j) {
        const float bj = bo[j * 16 + c];
#pragma unroll
        for (int r = 0; r < 4; ++r) acc[j][r] += bj;
    }
    float inv_[4];
#pragma unroll
    for (int r = 0; r < 4; ++r) {
        float s = 0.f;
#pragma unroll
        for (int j = 0; j < 16; ++j) s += acc[j][r] * acc[j][r];
        s = qred_add(s);
        inv_[r] = 1.f / fmaxf(sqrtf(s), 1e-12f);
    }

    float mk[4];                                   // row mask, mapping row = quad*4+r
#pragma unroll
    for (int r = 0; r < 4; ++r) mk[r] = mask[row0 + quad * 4 + r];

    // v = tanh(t/||t||): vu partials in-register, write v (bf16) into xs (reuse).
    // LAST read of GEMM1's acc -- dead after this loop (register reuse by GEMM2).
    float vup[4] = {0.f, 0.f, 0.f, 0.f};
#pragma unroll
    for (int j = 0; j < 16; ++j) {
        const float uj = u[j * 16 + c];
#pragma unroll
        for (int r = 0; r < 4; ++r) {
            const float tv = acc[j][r] * inv_[r];
            const float e2 = __expf(2.f * tv);
            const float v  = (e2 - 1.f) * __frcp_rn(e2 + 1.f);
            vup[r] += v * uj;
            xs[(quad * 4 + r) * XP + j * 16 + c] = (__bf16)v;
        }
    }
    // full vu per row entirely in-register; alphas numerator out now
    float ev_[4];
#pragma unroll
    for (int r = 0; r < 4; ++r) {
        const float vu = qred_add(vup[r]);
        ev_[r] = __expf(vu) * mk[r];
        if (c == r) e_out[row0 + quad * 4 + r] = ev_[r];   // static index, 1 lane/row
    }

    // ---- GEMM2: vuo = v @ Uo  (same acc registers)
#pragma unroll
    for (int j = 0; j < 16; ++j) acc[j] = (f32x4){0.f, 0.f, 0.f, 0.f};
    asm volatile("s_waitcnt lgkmcnt(0)" ::: "memory");  // cross-lane RAW: v tile visible
#pragma unroll
    for (int kk = 0; kk < 8; ++kk) {
        const bf16x8 a = *(const bf16x8*)(xs + c * XP + kk * 32 + quad * 8);
#pragma unroll
        for (int j = 0; j < 16; ++j) {
            const bf16x8 b = Uf8[(kk * 16 + j) * 64 + lane];
            acc[j] = __builtin_amdgcn_mfma_f32_16x16x32_bf16(a, b, acc[j], 0, 0, 0);
        }
    }

    // betas numerator + in-register row sums (no max shift: |vuo| <= ~10, cancels)
    float rs_[4];
#pragma unroll
    for (int r = 0; r < 4; ++r) {
        const float m = mk[r];
        float s = 0.f;
#pragma unroll
        for (int j = 0; j < 16; ++j) {
            const float e = __expf(acc[j][r] * m) * m;
            acc[j][r] = e;
            s += e;
        }
        s = qred_add(s);
        rs_[r] = 1.f / ((s == 0.f) ? 1.f : s);
    }

    // ---- epilogue: per-64-col chunk LDS transpose -> coalesced nontemporal
    //      f32x4 stores, fused out-partials with x re-read (L2-hot, same 16 KB).
    //      Rows stay in the COMPUTE mapping (quad reads its own rows): ev_/rs_
    //      need no redistribution.
    f32x4 opart[4];
#pragma unroll
    for (int ch = 0; ch < 4; ++ch) opart[ch] = (f32x4){0.f, 0.f, 0.f, 0.f};
#pragma unroll
    for (int ch = 0; ch < 4; ++ch) {
        asm volatile("s_waitcnt lgkmcnt(0)" ::: "memory");  // WAR: prior xs/trans reads done
#pragma unroll
        for (int jj = 0; jj < 4; ++jj)
#pragma unroll
            for (int r = 0; r < 4; ++r)
                trans[(quad * 4 + r) * TP + jj * 16 + c] = acc[ch * 4 + jj][r];
        asm volatile("s_waitcnt lgkmcnt(0)" ::: "memory");  // RAW: writes visible
#pragma unroll
        for (int p = 0; p < 4; ++p) {
            f32x4 b4 = *(const f32x4*)&trans[(quad * 4 + p) * TP + c * 4];
            const float rsv = rs_[p];
            b4[0] *= rsv; b4[1] *= rsv; b4[2] *= rsv; b4[3] *= rsv;
            const size_t goff = (size_t)(row0 + quad * 4 + p) * D_ + ch * 64 + c * 4;
            __builtin_nontemporal_store(b4, (f32x4*)&betas[goff]); // never re-read
            const float evv = ev_[p];
            if (evv != 0.f) {                               // quad-uniform skip
                const f32x4 x4 = *(const f32x4*)&x[goff];
                opart[ch][0] += evv * b4[0] * x4[0];
                opart[ch][1] += evv * b4[1] * x4[1];
                opart[ch][2] += evv * b4[2] * x4[2];
                opart[ch][3] += evv * b4[3] * x4[3];
            }
        }
    }
    // reduce out-partials across the 4 quads (rows); cols identical per c
#pragma unroll
    for (int ch = 0; ch < 4; ++ch)
#pragma unroll
        for (int k = 0; k < 4; ++k) {
            opart[ch][k] += __shfl_xor(opart[ch][k], 16);
            opart[ch][k] += __shfl_xor(opart[ch][k], 32);
        }
    if (lane < 16) {
        if (use_part) {
#pragma unroll
            for (int ch = 0; ch < 4; ++ch)
                *(f32x4*)&part[(size_t)blockIdx.x * D_ + ch * 64 + c * 4] = opart[ch];
        } else {
            const int b = row0 >> 10;
#pragma unroll
            for (int ch = 0; ch < 4; ++ch)
#pragma unroll
                for (int k = 0; k < 4; ++k)
                    atomicAdd(&outraw[b * D_ + ch * 64 + c * 4 + k], opart[ch][k]);
        }
    }
}

// ---- final: Z per batch, normalize alphas in place, reduce out partials.
__global__ __launch_bounds__(256) void k_fin(
    const float* __restrict__ part, float* __restrict__ e_alphas,
    float* __restrict__ out, const int use_part)
{
    const int b = blockIdx.x;
    const int tid = threadIdx.x, lane = tid & 63, wid = tid >> 6;
    __shared__ float red[4];
    const int base = b * S_;
    float ev[4];
#pragma unroll
    for (int k = 0; k < 4; ++k) ev[k] = e_alphas[base + tid + 256 * k];
    float s = ev[0] + ev[1] + ev[2] + ev[3];
    s = wred_add(s);
    if (lane == 0) red[wid] = s;
    __syncthreads();
    const float Z = red[0] + red[1] + red[2] + red[3];
    const float Zr = 1.f / ((Z == 0.f) ? 1.f : Z);
#pragma unroll
    for (int k = 0; k < 4; ++k) e_alphas[base + tid + 256 * k] = ev[k] * Zr;

    float acc;
    if (use_part) {
        acc = 0.f;
#pragma unroll
        for (int k = 0; k < S_ / ROWS; ++k) acc += part[(size_t)(b * (S_ / ROWS) + k) * D_ + tid];
    } else {
        acc = out[b * D_ + tid];
    }
    out[b * D_ + tid] = acc * Zr;
}

extern "C" void kernel_launch(void* const* d_in, const int* in_sizes, int n_in,
                              void* d_out, int out_size, void* d_ws, size_t ws_size,
                              hipStream_t stream) {
    const float* x    = (const float*)d_in[0];
    const float* mask = (const float*)d_in[1];
    const float* W    = (const float*)d_in[2];
    const float* bo   = (const float*)d_in[3];
    const float* u    = (const float*)d_in[4];
    const float* Uo   = (const float*)d_in[5];

    float* out    = (float*)d_out;             // [B, 256]
    float* alphas = out + B_ * D_;             // [B, S]
    float* betas  = alphas + (size_t)B_ * S_;  // [B, S, 256]

    __bf16* Wf = (__bf16*)d_ws;                // 128 KB
    __bf16* Uf = Wf + 65536;                   // 128 KB
    float* part = (float*)(Uf + 65536);        // 8192*256*4 = 8 MB (if it fits)

    const int nblk = B_ * S_ / ROWS;           // 8192
    const size_t need = 2 * 65536 * sizeof(__bf16) + (size_t)nblk * D_ * sizeof(float);
    const int use_part = (ws_size >= need) ? 1 : 0;

    if (!use_part)
        hipMemsetAsync(out, 0, (size_t)B_ * D_ * sizeof(float), stream);
    k_prep<<<256, 256, 0, stream>>>(W, Uo, Wf, Uf);
    k_rows<<<nblk, 64, 0, stream>>>(x, mask, Wf, bo, u, Uf, alphas, betas, part, out, use_part);
    k_fin <<<B_,   256, 0, stream>>>(part, alphas, out, use_part);
}

// Round 9
// 112.038 us; speedup vs baseline: 2.3433x; 2.3433x over previous
//
#include <hip/hip_runtime.h>
#include <math.h>

#define B_ 128
#define S_ 1024
#define D_ 256          // D == A == O == 256
#define XP 264          // LDS bf16 row pitch for x/v tile (528 B, 16B-aligned)
#define TP 68           // LDS fp32 row pitch for transpose buffer (272 B, 16B-aligned)
#define ROWS 32         // rows per block

using bf16x8 = __attribute__((ext_vector_type(8))) __bf16;
using bf16x4 = __attribute__((ext_vector_type(4))) __bf16;
using f32x4  = __attribute__((ext_vector_type(4))) float;

__device__ __forceinline__ float qred_add(float v) {   // reduce across 16-lane group
    v += __shfl_xor(v, 1); v += __shfl_xor(v, 2);
    v += __shfl_xor(v, 4); v += __shfl_xor(v, 8);
    return v;
}
__device__ __forceinline__ float wred_add(float x) {
#pragma unroll
    for (int off = 32; off > 0; off >>= 1) x += __shfl_xor(x, off, 64);
    return x;
}

// ---- prep: pack W, Uo (fp32 row-major [k][n]) into B-fragment-linear bf16.
__global__ __launch_bounds__(256) void k_prep(
    const float* __restrict__ W, const float* __restrict__ Uo,
    __bf16* __restrict__ Wf, __bf16* __restrict__ Uf)
{
    const int e = blockIdx.x * 256 + threadIdx.x;   // 0..65535
    const int frag = e >> 9, rem = e & 511;
    const int lane = rem >> 3, j = rem & 7;
    const int kk = frag >> 4, tn = frag & 15;
    const int k = kk * 32 + (lane >> 4) * 8 + j;
    const int n = tn * 16 + (lane & 15);
    Wf[e] = (__bf16)W[k * 256 + n];
    Uf[e] = (__bf16)Uo[k * 256 + n];
}

// ---- kernel A: stage x -> GEMM1 -> norm -> tanh -> vu -> export v-fragments.
// ONE 32-AGPR accumulator lifetime + ~50 V working set: (256,4)'s 128 cap fits
// by demand arithmetic (round-3's spill had TWO acc lifetimes + epilogue live).
// v-fragments (GEMM2 A-operands, 16 KB/block) go into the first 16 KB of this
// block's OWN 32 KB betas slot -- k_g2 reads them before its barrier and
// overwrites the slot after it. No cross-block overlap by construction.
__global__ __launch_bounds__(256, 4) void k_g1(
    const float* __restrict__ x, const float* __restrict__ mask,
    const __bf16* __restrict__ Wf, const float* __restrict__ bo,
    const float* __restrict__ u,
    float* __restrict__ e_out,    // [B*S] unnormalized exp(vu)*mask (alphas region)
    float* __restrict__ vscr)     // betas region used as v-fragment scratch
{
    __shared__ __align__(16) char smem[ROWS * XP * 2];   // 16896 B
    __bf16* xs = (__bf16*)smem;
    __shared__ float red[4][ROWS];
    __shared__ float red2[4][ROWS];
    const int tid = threadIdx.x, lane = tid & 63, w = tid >> 6;
    const int quad = lane >> 4, c = lane & 15;
    const int row0 = blockIdx.x * ROWS;
    const bf16x8* Wf8 = (const bf16x8*)Wf;

    // stage x[32][256] fp32 -> bf16 LDS
    {
        const float4* xg = (const float4*)(x + (size_t)row0 * D_);
#pragma unroll
        for (int it = 0; it < 8; ++it) {
            const int r = it * 4 + w;
            const float4 t = xg[r * 64 + lane];
            bf16x4 h; h[0] = (__bf16)t.x; h[1] = (__bf16)t.y; h[2] = (__bf16)t.z; h[3] = (__bf16)t.w;
            *(bf16x4*)(xs + r * XP + lane * 4) = h;
        }
    }
    __syncthreads();                                   // sync0: x staged

    // ---- GEMM1: t = x @ W  (wave w owns cols [64w, 64w+64))
    f32x4 acc[2][4];
#pragma unroll
    for (int i = 0; i < 2; ++i)
#pragma unroll
        for (int j = 0; j < 4; ++j) acc[i][j] = (f32x4){0.f, 0.f, 0.f, 0.f};
#pragma unroll
    for (int kk = 0; kk < 8; ++kk) {
        bf16x8 a[2], b[4];
#pragma unroll
        for (int i = 0; i < 2; ++i)
            a[i] = *(const bf16x8*)(xs + (i * 16 + c) * XP + kk * 32 + quad * 8);
#pragma unroll
        for (int j = 0; j < 4; ++j)
            b[j] = Wf8[(kk * 16 + w * 4 + j) * 64 + lane];
#pragma unroll
        for (int i = 0; i < 2; ++i)
#pragma unroll
            for (int j = 0; j < 4; ++j)
                acc[i][j] = __builtin_amdgcn_mfma_f32_16x16x32_bf16(a[i], b[j], acc[i][j], 0, 0, 0);
    }

    // bias + row sum-of-squares partials
#pragma unroll
    for (int j = 0; j < 4; ++j) {
        const float bj = bo[w * 64 + j * 16 + c];
#pragma unroll
        for (int i = 0; i < 2; ++i)
#pragma unroll
            for (int r = 0; r < 4; ++r) acc[i][j][r] += bj;
    }
    {
        float myv = 0.f;
#pragma unroll
        for (int i = 0; i < 2; ++i)
#pragma unroll
            for (int r = 0; r < 4; ++r) {
                float s = 0.f;
#pragma unroll
                for (int j = 0; j < 4; ++j) s += acc[i][j][r] * acc[i][j][r];
                const float p = qred_add(s);
                if (c == i * 4 + r) myv = p;
            }
        if (c < 8) red[w][(c >> 2) * 16 + quad * 4 + (c & 3)] = myv;
    }
    __syncthreads();                                   // (a): norm partials visible

    float inv[2][4];
#pragma unroll
    for (int i = 0; i < 2; ++i)
#pragma unroll
        for (int r = 0; r < 4; ++r) {
            const int row = i * 16 + quad * 4 + r;
            const float t = red[0][row] + red[1][row] + red[2][row] + red[3][row];
            inv[i][r] = 1.f / fmaxf(sqrtf(t), 1e-12f);
        }

    // v = tanh(t/||t||): vu partials, write v (bf16) into xs (reuse)
    float uj[4];
#pragma unroll
    for (int j = 0; j < 4; ++j) uj[j] = u[w * 64 + j * 16 + c];
    float vup[2][4];
#pragma unroll
    for (int i = 0; i < 2; ++i)
#pragma unroll
        for (int r = 0; r < 4; ++r) vup[i][r] = 0.f;
#pragma unroll
    for (int i = 0; i < 2; ++i)
#pragma unroll
        for (int j = 0; j < 4; ++j)
#pragma unroll
            for (int r = 0; r < 4; ++r) {
                const float tv = acc[i][j][r] * inv[i][r];
                const float e2 = __expf(2.f * tv);
                const float v  = (e2 - 1.f) * __frcp_rn(e2 + 1.f);
                vup[i][r] += v * uj[j];
                xs[(i * 16 + quad * 4 + r) * XP + (w * 64 + j * 16 + c)] = (__bf16)v;
            }
    {
        float myv = 0.f;
#pragma unroll
        for (int i = 0; i < 2; ++i)
#pragma unroll
            for (int r = 0; r < 4; ++r) {
                const float p = qred_add(vup[i][r]);
                if (c == i * 4 + r) myv = p;
            }
        if (c < 8) red2[w][(c >> 2) * 16 + quad * 4 + (c & 3)] = myv;
    }
    __syncthreads();                                   // (b): v tile AND vu partials visible

    if (tid < ROWS) {
        const float vu = red2[0][tid] + red2[1][tid] + red2[2][tid] + red2[3][tid];
        e_out[row0 + tid] = __expf(vu) * mask[row0 + tid];
    }

    // ---- export GEMM2 A-fragments: wave w handles kk = 2w, 2w+1.
    // frag index f = (kk*2+i)*64 + lane; 16 B/lane contiguous -> 1 KB/store-group.
    bf16x8* vf8 = (bf16x8*)(vscr + (size_t)blockIdx.x * (ROWS * D_));  // first 16 KB of slot
    const int kkb = 2 * w;
#pragma unroll
    for (int kk2 = 0; kk2 < 2; ++kk2)
#pragma unroll
        for (int i = 0; i < 2; ++i) {
            const bf16x8 av = *(const bf16x8*)(xs + (i * 16 + c) * XP + (kkb + kk2) * 32 + quad * 8);
            vf8[((kkb + kk2) * 2 + i) * 64 + lane] = av;   // cacheable: L3-resident for k_g2
        }
}

// ---- kernel B: GEMM2 -> beta softmax -> epilogue (transpose, betas, out partials).
// One 32-AGPR acc + ~55 V: fits (256,4). Single barrier. Reads v-fragments from
// the betas slot, overwrites the slot with final betas strictly after the barrier.
__global__ __launch_bounds__(256, 4) void k_g2(
    const float* __restrict__ x, const float* __restrict__ mask,
    const __bf16* __restrict__ Uf, const float* __restrict__ e_out,
    float* betas,                 // read v-frags, then write final betas (same buffer)
    float* __restrict__ part,     // [gridDim.x, 256] per-block out partials (ws)
    float* __restrict__ outraw,   // [B,256] atomic fallback accumulator
    const int use_part)
{
    __shared__ __align__(16) float trans[4][16 * TP];  // 17408 B, wave-private slices
    __shared__ float red[4][ROWS];
    const int tid = threadIdx.x, lane = tid & 63, w = tid >> 6;
    const int quad = lane >> 4, c = lane & 15;
    const int hi = lane >> 4, c4 = lane & 15;
    const int row0 = blockIdx.x * ROWS;
    const bf16x8* Uf8 = (const bf16x8*)Uf;
    const bf16x8* vf8 = (const bf16x8*)(betas + (size_t)blockIdx.x * (ROWS * D_));

    // ---- GEMM2: vuo = v @ Uo  (A-fragments direct from global, L3-hot)
    f32x4 acc[2][4];
#pragma unroll
    for (int i = 0; i < 2; ++i)
#pragma unroll
        for (int j = 0; j < 4; ++j) acc[i][j] = (f32x4){0.f, 0.f, 0.f, 0.f};
#pragma unroll
    for (int kk = 0; kk < 8; ++kk) {
        bf16x8 a[2], b[4];
#pragma unroll
        for (int i = 0; i < 2; ++i)
            a[i] = vf8[(kk * 2 + i) * 64 + lane];
#pragma unroll
        for (int j = 0; j < 4; ++j)
            b[j] = Uf8[(kk * 16 + w * 4 + j) * 64 + lane];
#pragma unroll
        for (int i = 0; i < 2; ++i)
#pragma unroll
            for (int j = 0; j < 4; ++j)
                acc[i][j] = __builtin_amdgcn_mfma_f32_16x16x32_bf16(a[i], b[j], acc[i][j], 0, 0, 0);
    }

    // betas numerator: exp(vuo*mask)*mask  (no max shift: |vuo| <= ~10, cancels exactly)
#pragma unroll
    for (int i = 0; i < 2; ++i)
#pragma unroll
        for (int r = 0; r < 4; ++r) {
            const float m = mask[row0 + i * 16 + quad * 4 + r];
#pragma unroll
            for (int j = 0; j < 4; ++j)
                acc[i][j][r] = __expf(acc[i][j][r] * m) * m;
        }
    // beta row-sum partials -> red
    {
        float myv = 0.f;
#pragma unroll
        for (int i = 0; i < 2; ++i)
#pragma unroll
            for (int r = 0; r < 4; ++r) {
                float s = 0.f;
#pragma unroll
                for (int j = 0; j < 4; ++j) s += acc[i][j][r];
                const float p = qred_add(s);
                if (c == i * 4 + r) myv = p;
            }
        if (c < 8) red[w][(c >> 2) * 16 + quad * 4 + (c & 3)] = myv;
    }
    __syncthreads();    // the ONLY barrier: beta sums visible AND all v-frag reads consumed

    // ev + rs in store mapping: row rr = i*16 + hi + p*4
    float ev[2][4], rs[2][4];
#pragma unroll
    for (int i = 0; i < 2; ++i)
#pragma unroll
        for (int p = 0; p < 4; ++p) {
            const int rr = i * 16 + hi + p * 4;
            ev[i][p] = e_out[row0 + rr];                  // unnormalized exp(vu)*mask from k_g1
            const float s = red[0][rr] + red[1][rr] + red[2][rr] + red[3][rr];
            rs[i][p] = 1.f / ((s == 0.f) ? 1.f : s);
        }

    // ---- epilogue: LDS transpose (wave-private slice) -> coalesced float4 stores,
    //      fused out-partials with coalesced masked x re-read. Betas writes land in
    //      this block's own slot (clobbering its v-frags, already consumed).
    float* tw = trans[w];
    f32x4 opart = (f32x4){0.f, 0.f, 0.f, 0.f};
#pragma unroll
    for (int i = 0; i < 2; ++i) {
        asm volatile("s_waitcnt lgkmcnt(0)" ::: "memory");  // prior red/trans reads drained (WAR)
#pragma unroll
        for (int j = 0; j < 4; ++j)
#pragma unroll
            for (int r = 0; r < 4; ++r)
                tw[(quad * 4 + r) * TP + j * 16 + c] = acc[i][j][r];
        asm volatile("s_waitcnt lgkmcnt(0)" ::: "memory");  // writes visible (RAW)
#pragma unroll
        for (int p = 0; p < 4; ++p) {
            const int rl = hi + p * 4;                      // local row 0..15
            f32x4 b4 = *(const f32x4*)&tw[rl * TP + c4 * 4];
            const float rsv = rs[i][p];
            b4[0] *= rsv; b4[1] *= rsv; b4[2] *= rsv; b4[3] *= rsv;
            const size_t goff = (size_t)(row0 + i * 16 + rl) * D_ + w * 64 + c4 * 4;
            __builtin_nontemporal_store(b4, (f32x4*)&betas[goff]); // never re-read
            const float evv = ev[i][p];
            if (evv != 0.f) {                               // 16-lane-uniform skip
                const f32x4 x4 = *(const f32x4*)&x[goff];
                opart[0] += evv * b4[0] * x4[0];
                opart[1] += evv * b4[1] * x4[1];
                opart[2] += evv * b4[2] * x4[2];
                opart[3] += evv * b4[3] * x4[3];
            }
        }
    }
#pragma unroll
    for (int k = 0; k < 4; ++k) {
        opart[k] += __shfl_xor(opart[k], 16);
        opart[k] += __shfl_xor(opart[k], 32);
    }
    if (lane < 16) {
        const int col = w * 64 + c4 * 4;
        if (use_part) {
            *(f32x4*)&part[(size_t)blockIdx.x * D_ + col] = opart;
        } else {
            const int b = row0 >> 10;
#pragma unroll
            for (int k = 0; k < 4; ++k) atomicAdd(&outraw[b * D_ + col + k], opart[k]);
        }
    }
}

// ---- final: Z per batch, normalize alphas in place, reduce out partials.
__global__ __launch_bounds__(256) void k_fin(
    const float* __restrict__ part, float* __restrict__ e_alphas,
    float* __restrict__ out, const int use_part)
{
    const int b = blockIdx.x;
    const int tid = threadIdx.x, lane = tid & 63, wid = tid >> 6;
    __shared__ float red[4];
    const int base = b * S_;
    float ev[4];
#pragma unroll
    for (int k = 0; k < 4; ++k) ev[k] = e_alphas[base + tid + 256 * k];
    float s = ev[0] + ev[1] + ev[2] + ev[3];
    s = wred_add(s);
    if (lane == 0) red[wid] = s;
    __syncthreads();
    const float Z = red[0] + red[1] + red[2] + red[3];
    const float Zr = 1.f / ((Z == 0.f) ? 1.f : Z);
#pragma unroll
    for (int k = 0; k < 4; ++k) e_alphas[base + tid + 256 * k] = ev[k] * Zr;

    float acc;
    if (use_part) {
        acc = 0.f;
#pragma unroll
        for (int k = 0; k < 32; ++k) acc += part[(size_t)(b * 32 + k) * D_ + tid];
    } else {
        acc = out[b * D_ + tid];
    }
    out[b * D_ + tid] = acc * Zr;
}

extern "C" void kernel_launch(void* const* d_in, const int* in_sizes, int n_in,
                              void* d_out, int out_size, void* d_ws, size_t ws_size,
                              hipStream_t stream) {
    const float* x    = (const float*)d_in[0];
    const float* mask = (const float*)d_in[1];
    const float* W    = (const float*)d_in[2];
    const float* bo   = (const float*)d_in[3];
    const float* u    = (const float*)d_in[4];
    const float* Uo   = (const float*)d_in[5];

    float* out    = (float*)d_out;             // [B, 256]
    float* alphas = out + B_ * D_;             // [B, S]
    float* betas  = alphas + (size_t)B_ * S_;  // [B, S, 256]

    __bf16* Wf = (__bf16*)d_ws;                // 128 KB
    __bf16* Uf = Wf + 65536;                   // 128 KB
    float* part = (float*)(Uf + 65536);        // 4096*256*4 = 4 MB (if it fits)

    const int nblk = B_ * S_ / ROWS;           // 4096
    const size_t need = 2 * 65536 * sizeof(__bf16) + (size_t)nblk * D_ * sizeof(float);
    const int use_part = (ws_size >= need) ? 1 : 0;

    if (!use_part)
        hipMemsetAsync(out, 0, (size_t)B_ * D_ * sizeof(float), stream);
    k_prep<<<256, 256, 0, stream>>>(W, Uo, Wf, Uf);
    k_g1 <<<nblk, 256, 0, stream>>>(x, mask, Wf, bo, u, alphas, betas);
    k_g2 <<<nblk, 256, 0, stream>>>(x, mask, Uf, alphas, betas, part, out, use_part);
    k_fin<<<B_,   256, 0, stream>>>(part, alphas, out, use_part);
}

// Round 11
// 90.149 us; speedup vs baseline: 2.9123x; 1.2428x over previous
//
#include <hip/hip_runtime.h>
#include <math.h>

#define B_ 128
#define S_ 1024
#define D_ 256          // D == A == O == 256
#define XP 264          // LDS bf16 row pitch for x/v tile (528 B, 16B-aligned)
#define TP 68           // LDS fp32 row pitch for transpose buffer (272 B, 16B-aligned)
#define ROWS 32         // rows per block
#define LOG2E  1.44269504f
#define LOG2E2 2.88539008f

using bf16x8 = __attribute__((ext_vector_type(8))) __bf16;
using bf16x4 = __attribute__((ext_vector_type(4))) __bf16;
using f32x4  = __attribute__((ext_vector_type(4))) float;

__device__ __forceinline__ float qred_add(float v) {   // reduce across 16-lane group
    v += __shfl_xor(v, 1); v += __shfl_xor(v, 2);
    v += __shfl_xor(v, 4); v += __shfl_xor(v, 8);
    return v;
}
__device__ __forceinline__ float wred_add(float x) {
#pragma unroll
    for (int off = 32; off > 0; off >>= 1) x += __shfl_xor(x, off, 64);
    return x;
}

// ---- prep: pack W, Uo (fp32 row-major [k][n]) into B-fragment-linear bf16.
__global__ __launch_bounds__(256) void k_prep(
    const float* __restrict__ W, const float* __restrict__ Uo,
    __bf16* __restrict__ Wf, __bf16* __restrict__ Uf)
{
    const int e = blockIdx.x * 256 + threadIdx.x;   // 0..65535
    const int frag = e >> 9, rem = e & 511;
    const int lane = rem >> 3, j = rem & 7;
    const int kk = frag >> 4, tn = frag & 15;
    const int k = kk * 32 + (lane >> 4) * 8 + j;
    const int n = tn * 16 + (lane & 15);
    Wf[e] = (__bf16)W[k * 256 + n];
    Uf[e] = (__bf16)Uo[k * 256 + n];
}

// ---- main fused kernel: 32 rows/block, 4 waves; wave w owns cols [64w, 64w+64).
// Round-4 structure (best: 104.6 us) + VALU trim: raw v_rcp/v_rsq on bf16-bound
// paths (frcp_rn's Newton refinement is invisible after bf16 truncation),
// exp2-folding (2log2e into inv scale; log2e into beta mask), single-drain
// epilogue (per-wave 32-row trans slice: 4 lgkm drains -> 1).
// ROUND-10 BUG FIXED: beta-partial store must be GUARDED `if (c<8)` -- the
// ternary form made lanes c>=8 do an OOB read-modify-write into the neighbor
// wave's red[] (racing its fresh partials) -> absmax 1.56e-4. One-line revert.
// Falsifiers: WRITE_SIZE > 140,000 KB or VGPR > 80 = spill/regalloc perturbed.
__global__ __launch_bounds__(256, 3) void k_rows(
    const float* __restrict__ x, const float* __restrict__ mask,
    const __bf16* __restrict__ Wf, const float* __restrict__ bo,
    const float* __restrict__ u, const __bf16* __restrict__ Uf,
    float* __restrict__ e_out,    // [B*S] unnormalized exp(vu)*mask (alphas region)
    float* __restrict__ betas,    // [B*S, 256]
    float* __restrict__ part,     // [gridDim.x, 256] per-block out partials (ws)
    float* __restrict__ outraw,   // [B,256] atomic fallback accumulator
    const int use_part)
{
    // trans: 4 waves x 32 rows x TP fp32 = 34816 B; xs (bf16 x/v tile, 16896 B)
    // aliases its head (dead by the time trans is written, barrier (d) orders).
    __shared__ __align__(16) char smem[4 * 32 * TP * 4];
    __bf16* xs   = (__bf16*)smem;
    float* trans = (float*)smem;
    __shared__ float red[4][ROWS];    // ||t||^2 partials, then beta row-sum partials
    __shared__ float red2[4][ROWS];   // vu partials
    const int tid = threadIdx.x, lane = tid & 63, w = tid >> 6;
    const int quad = lane >> 4, c = lane & 15;
    const int hi = lane >> 4, c4 = lane & 15;      // store-phase decomposition
    const int row0 = blockIdx.x * ROWS;
    const bf16x8* Wf8 = (const bf16x8*)Wf;
    const bf16x8* Uf8 = (const bf16x8*)Uf;

    // stage x[32][256] fp32 -> bf16 LDS
    {
        const float4* xg = (const float4*)(x + (size_t)row0 * D_);
#pragma unroll
        for (int it = 0; it < 8; ++it) {
            const int r = it * 4 + w;
            const float4 t = xg[r * 64 + lane];
            bf16x4 h; h[0] = (__bf16)t.x; h[1] = (__bf16)t.y; h[2] = (__bf16)t.z; h[3] = (__bf16)t.w;
            *(bf16x4*)(xs + r * XP + lane * 4) = h;
        }
    }

    __syncthreads();                                   // sync0: x staged

    // ---- GEMM1: t = x @ W
    f32x4 acc[2][4];                                   // reused by GEMM2 (32 AGPR total)
#pragma unroll
    for (int i = 0; i < 2; ++i)
#pragma unroll
        for (int j = 0; j < 4; ++j) acc[i][j] = (f32x4){0.f, 0.f, 0.f, 0.f};
#pragma unroll
    for (int kk = 0; kk < 8; ++kk) {
        bf16x8 a[2], b[4];
#pragma unroll
        for (int i = 0; i < 2; ++i)
            a[i] = *(const bf16x8*)(xs + (i * 16 + c) * XP + kk * 32 + quad * 8);
#pragma unroll
        for (int j = 0; j < 4; ++j)
            b[j] = Wf8[(kk * 16 + w * 4 + j) * 64 + lane];
#pragma unroll
        for (int i = 0; i < 2; ++i)
#pragma unroll
            for (int j = 0; j < 4; ++j)
                acc[i][j] = __builtin_amdgcn_mfma_f32_16x16x32_bf16(a[i], b[j], acc[i][j], 0, 0, 0);
    }

    // bias + row sum-of-squares partials
#pragma unroll
    for (int j = 0; j < 4; ++j) {
        const float bj = bo[w * 64 + j * 16 + c];
#pragma unroll
        for (int i = 0; i < 2; ++i)
#pragma unroll
            for (int r = 0; r < 4; ++r) acc[i][j][r] += bj;
    }
    {
        float myv = 0.f;
#pragma unroll
        for (int i = 0; i < 2; ++i)
#pragma unroll
            for (int r = 0; r < 4; ++r) {
                float s = 0.f;
#pragma unroll
                for (int j = 0; j < 4; ++j) s += acc[i][j][r] * acc[i][j][r];
                const float p = qred_add(s);
                if (c == i * 4 + r) myv = p;
            }
        if (c < 8) red[w][(c >> 2) * 16 + quad * 4 + (c & 3)] = myv;
    }
    __syncthreads();                                   // (a): norm partials visible;
                                                       //      GEMM1 xs reads done (v-write WAR)

    // inv2 = 2*log2e / ||t||: one v_rsq (clamp inside: t>=1e-24 <=> norm>=1e-12).
    // exp(2*t/||t||) becomes exp2(acc*inv2) -- folds the 2x and log2e muls away.
    float inv2[2][4];
#pragma unroll
    for (int i = 0; i < 2; ++i)
#pragma unroll
        for (int r = 0; r < 4; ++r) {
            const int row = i * 16 + quad * 4 + r;
            const float t = red[0][row] + red[1][row] + red[2][row] + red[3][row];
            inv2[i][r] = __builtin_amdgcn_rsqf(fmaxf(t, 1e-24f)) * LOG2E2;
        }

    // v = tanh(t/||t||): vu partials, write v (bf16) into xs (reuse).
    // LAST read of GEMM1's acc -- dead after this loop (enables AGPR reuse).
    // Raw v_rcp: v is truncated to bf16, refinement ulps are invisible.
    float uj[4];
#pragma unroll
    for (int j = 0; j < 4; ++j) uj[j] = u[w * 64 + j * 16 + c];
    float vup[2][4];
#pragma unroll
    for (int i = 0; i < 2; ++i)
#pragma unroll
        for (int r = 0; r < 4; ++r) vup[i][r] = 0.f;
#pragma unroll
    for (int i = 0; i < 2; ++i)
#pragma unroll
        for (int j = 0; j < 4; ++j)
#pragma unroll
            for (int r = 0; r < 4; ++r) {
                const float e2 = __builtin_amdgcn_exp2f(acc[i][j][r] * inv2[i][r]);
                const float v  = (e2 - 1.f) * __builtin_amdgcn_rcpf(e2 + 1.f);
                vup[i][r] += v * uj[j];
                xs[(i * 16 + quad * 4 + r) * XP + (w * 64 + j * 16 + c)] = (__bf16)v;
            }
    // vu partials into red2 BEFORE the barrier (red2 has no prior readers).
    {
        float myv = 0.f;
#pragma unroll
        for (int i = 0; i < 2; ++i)
#pragma unroll
            for (int r = 0; r < 4; ++r) {
                const float p = qred_add(vup[i][r]);
                if (c == i * 4 + r) myv = p;
            }
        if (c < 8) red2[w][(c >> 2) * 16 + quad * 4 + (c & 3)] = myv;
    }
    __syncthreads();                                   // (b): v tile AND vu partials visible

    // early e_out store (ev for epilogue recomputed after (d) from red2, intact)
    if (tid < ROWS) {
        const float vu = red2[0][tid] + red2[1][tid] + red2[2][tid] + red2[3][tid];
        e_out[row0 + tid] = __expf(vu) * mask[row0 + tid];
    }

    // ---- GEMM2: vuo = v @ Uo  (accumulates into the SAME acc array -> AGPR reuse)
#pragma unroll
    for (int i = 0; i < 2; ++i)
#pragma unroll
        for (int j = 0; j < 4; ++j) acc[i][j] = (f32x4){0.f, 0.f, 0.f, 0.f};
#pragma unroll
    for (int kk = 0; kk < 8; ++kk) {
        bf16x8 a[2], b[4];
#pragma unroll
        for (int i = 0; i < 2; ++i)
            a[i] = *(const bf16x8*)(xs + (i * 16 + c) * XP + kk * 32 + quad * 8);
#pragma unroll
        for (int j = 0; j < 4; ++j)
            b[j] = Uf8[(kk * 16 + w * 4 + j) * 64 + lane];
#pragma unroll
        for (int i = 0; i < 2; ++i)
#pragma unroll
            for (int j = 0; j < 4; ++j)
                acc[i][j] = __builtin_amdgcn_mfma_f32_16x16x32_bf16(a[i], b[j], acc[i][j], 0, 0, 0);
    }

    // betas numerator: exp(vuo*m)*m = exp2(vuo*(m*log2e))*m  (no max shift:
    // |vuo| <= ~10, the shift cancels exactly in the ratio)
#pragma unroll
    for (int i = 0; i < 2; ++i)
#pragma unroll
        for (int r = 0; r < 4; ++r) {
            const float m  = mask[row0 + i * 16 + quad * 4 + r];
            const float m2 = m * LOG2E;
#pragma unroll
            for (int j = 0; j < 4; ++j)
                acc[i][j][r] = __builtin_amdgcn_exp2f(acc[i][j][r] * m2) * m;
        }
    // beta row-sum partials into red BEFORE the barrier (red's last reader was
    // inv2, pre-(b): barrier (b) orders -> no WAR hazard). GUARDED store (c<8):
    // unguarded form was round-10's OOB race.
    {
        float myv = 0.f;
#pragma unroll
        for (int i = 0; i < 2; ++i)
#pragma unroll
            for (int r = 0; r < 4; ++r) {
                float s = 0.f;
#pragma unroll
                for (int j = 0; j < 4; ++j) s += acc[i][j][r];
                const float p = qred_add(s);
                if (c == i * 4 + r) myv = p;
            }
        if (c < 8) red[w][(c >> 2) * 16 + quad * 4 + (c & 3)] = myv;
    }
    __syncthreads();                                   // (d): GEMM2 xs reads done (trans WAR)
                                                       //      AND beta sums visible

    // ev + rs in store mapping: row rr = i*16 + hi + p*4
    float ev[2][4], rs[2][4];
#pragma unroll
    for (int i = 0; i < 2; ++i)
#pragma unroll
        for (int p = 0; p < 4; ++p) {
            const int rr = i * 16 + hi + p * 4;
            const float vu = red2[0][rr] + red2[1][rr] + red2[2][rr] + red2[3][rr];
            ev[i][p] = __expf(vu) * mask[row0 + rr];
            const float s = red[0][rr] + red[1][rr] + red[2][rr] + red[3][rr];
            rs[i][p] = __builtin_amdgcn_rcpf((s == 0.f) ? 1.f : s);  // ~1ulp: fine for fp32 betas
        }

    // ---- epilogue: single-drain LDS transpose. Wave-private 32-row slice:
    // i=0 and i=1 go to disjoint halves -> ALL 32 writes, ONE lgkm drain, all reads.
    // (Barrier (d) already drained every wave's GEMM2 xs reads -> no initial WAR wait.)
    float* tw = trans + w * (32 * TP);
    f32x4 opart = (f32x4){0.f, 0.f, 0.f, 0.f};
#pragma unroll
    for (int i = 0; i < 2; ++i)
#pragma unroll
        for (int j = 0; j < 4; ++j)
#pragma unroll
            for (int r = 0; r < 4; ++r)
                tw[i * (16 * TP) + (quad * 4 + r) * TP + j * 16 + c] = acc[i][j][r];
    asm volatile("s_waitcnt lgkmcnt(0)" ::: "memory");  // RAW: all transpose writes visible
#pragma unroll
    for (int i = 0; i < 2; ++i)
#pragma unroll
        for (int p = 0; p < 4; ++p) {
            const int rl = hi + p * 4;                      // local row 0..15
            f32x4 b4 = *(const f32x4*)&tw[i * (16 * TP) + rl * TP + c4 * 4];
            const float rsv = rs[i][p];
            b4[0] *= rsv; b4[1] *= rsv; b4[2] *= rsv; b4[3] *= rsv;
            const size_t goff = (size_t)(row0 + i * 16 + rl) * D_ + w * 64 + c4 * 4;
            __builtin_nontemporal_store(b4, (f32x4*)&betas[goff]); // never re-read: keep L2 for x
            const float evv = ev[i][p];
            if (evv != 0.f) {                               // 16-lane-uniform skip
                const f32x4 x4 = *(const f32x4*)&x[goff];
                opart[0] += evv * b4[0] * x4[0];
                opart[1] += evv * b4[1] * x4[1];
                opart[2] += evv * b4[2] * x4[2];
                opart[3] += evv * b4[3] * x4[3];
            }
        }
    // reduce across the 4 row-groups
#pragma unroll
    for (int k = 0; k < 4; ++k) {
        opart[k] += __shfl_xor(opart[k], 16);
        opart[k] += __shfl_xor(opart[k], 32);
    }
    if (lane < 16) {
        const int col = w * 64 + c4 * 4;
        if (use_part) {
            *(f32x4*)&part[(size_t)blockIdx.x * D_ + col] = opart;
        } else {
            const int b = row0 >> 10;
#pragma unroll
            for (int k = 0; k < 4; ++k) atomicAdd(&outraw[b * D_ + col + k], opart[k]);
        }
    }
}

// ---- final: Z per batch, normalize alphas in place, reduce out partials.
__global__ __launch_bounds__(256) void k_fin(
    const float* __restrict__ part, float* __restrict__ e_alphas,
    float* __restrict__ out, const int use_part)
{
    const int b = blockIdx.x;
    const int tid = threadIdx.x, lane = tid & 63, wid = tid >> 6;
    __shared__ float red[4];
    const int base = b * S_;
    float ev[4];
#pragma unroll
    for (int k = 0; k < 4; ++k) ev[k] = e_alphas[base + tid + 256 * k];
    float s = ev[0] + ev[1] + ev[2] + ev[3];
    s = wred_add(s);
    if (lane == 0) red[wid] = s;
    __syncthreads();
    const float Z = red[0] + red[1] + red[2] + red[3];
    const float Zr = 1.f / ((Z == 0.f) ? 1.f : Z);
#pragma unroll
    for (int k = 0; k < 4; ++k) e_alphas[base + tid + 256 * k] = ev[k] * Zr;

    float acc;
    if (use_part) {
        acc = 0.f;
#pragma unroll
        for (int k = 0; k < 32; ++k) acc += part[(size_t)(b * 32 + k) * D_ + tid];
    } else {
        acc = out[b * D_ + tid];
    }
    out[b * D_ + tid] = acc * Zr;
}

extern "C" void kernel_launch(void* const* d_in, const int* in_sizes, int n_in,
                              void* d_out, int out_size, void* d_ws, size_t ws_size,
                              hipStream_t stream) {
    const float* x    = (const float*)d_in[0];
    const float* mask = (const float*)d_in[1];
    const float* W    = (const float*)d_in[2];
    const float* bo   = (const float*)d_in[3];
    const float* u    = (const float*)d_in[4];
    const float* Uo   = (const float*)d_in[5];

    float* out    = (float*)d_out;             // [B, 256]
    float* alphas = out + B_ * D_;             // [B, S]
    float* betas  = alphas + (size_t)B_ * S_;  // [B, S, 256]

    __bf16* Wf = (__bf16*)d_ws;                // 128 KB
    __bf16* Uf = Wf + 65536;                   // 128 KB
    float* part = (float*)(Uf + 65536);        // 4096*256*4 = 4 MB (if it fits)

    const int nblk = B_ * S_ / ROWS;           // 4096
    const size_t need = 2 * 65536 * sizeof(__bf16) + (size_t)nblk * D_ * sizeof(float);
    const int use_part = (ws_size >= need) ? 1 : 0;

    if (!use_part)
        hipMemsetAsync(out, 0, (size_t)B_ * D_ * sizeof(float), stream);
    k_prep<<<256, 256, 0, stream>>>(W, Uo, Wf, Uf);
    k_rows<<<nblk, 256, 0, stream>>>(x, mask, Wf, bo, u, Uf, alphas, betas, part, out, use_part);
    k_fin <<<B_,   256, 0, stream>>>(part, alphas, out, use_part);
}